// Round 2
// baseline (326.064 us; speedup 1.0000x reference)
//
#include <hip/hip_runtime.h>

typedef unsigned short ushort_t;
typedef __attribute__((ext_vector_type(4))) float f32x4;
typedef __attribute__((ext_vector_type(8))) short s16x8;
typedef __attribute__((ext_vector_type(8))) unsigned short u16x8;

#define NB 16         // dialogues
#define NL 54         // utterances per dialogue
#define NT (NB*NL)    // 864
#define NNODE (3*NT)  // 2592
#define NEDGE 912     // hyperedges = 16*(54+3)
#define HDIM 512
#define MATSZ (512*512)

__device__ __forceinline__ ushort_t f2b(float f){
  union {unsigned int i; float f;} x; x.f = f;
  unsigned int r = (x.i + 0x7fffu + ((x.i>>16)&1u))>>16;
  return (ushort_t)r;
}

// ---------------------------------------------------------------------------
// Kernel 0: transpose+convert all 16 fp32 weight matrices [K,N] -> bf16
// WT[w][n][k]; also zero the denoise accumulator.  grid (8,8,16), block 256
// ---------------------------------------------------------------------------
__global__ __launch_bounds__(256) void transpose_weights(
    const float* __restrict__ fc1, const float* __restrict__ hc,
    const float* __restrict__ m0, const float* __restrict__ m1,
    const float* __restrict__ ms, ushort_t* __restrict__ WT,
    float* __restrict__ acc)
{
  if (blockIdx.x==0 && blockIdx.y==0 && blockIdx.z==0 && threadIdx.x==0) *acc = 0.0f;
  int w = blockIdx.z;
  const float* src = (w==0) ? fc1
                   : (w<4)  ? hc + (size_t)(w-1)*MATSZ
                   : (w<8)  ? m0 + (size_t)(w-4)*MATSZ
                   : (w<12) ? m1 + (size_t)(w-8)*MATSZ
                            : ms + (size_t)(w-12)*MATSZ;
  ushort_t* dst = WT + (size_t)w*MATSZ;
  __shared__ float tile[64][65];
  int r0 = blockIdx.x*64, c0 = blockIdx.y*64;
  #pragma unroll
  for (int j=0;j<16;j++){
    int idx = j*256 + threadIdx.x;
    int r = idx>>6, c = idx&63;
    tile[r][c] = src[(size_t)(r0+r)*512 + c0 + c];
  }
  __syncthreads();
  #pragma unroll
  for (int j=0;j<16;j++){
    int idx = j*256 + threadIdx.x;
    int r = idx>>6, c = idx&63;
    dst[(size_t)(c0+r)*512 + r0 + c] = f2b(tile[c][r]);
  }
}

// ---------------------------------------------------------------------------
// GEMM: C[2592,512] = A[2592,512] @ W[512,512] (+bias)(+relu), fp32 in/out,
// bf16 MFMA internally.
// AMODE 0: A = feats (fp32 a/v/l + spk_emb via qmask argmax)
// AMODE 1: A = hypergraph node agg from edge buffer E (2-incidence combine)
// AMODE 2: A = fp32 matrix (Afp); gridDim.z=3 selects W0/W1/Wself of `layer`
// block 256 (4 waves), tile M=32 x N=128, K-step 64, mfma 16x16x32 bf16.
// ---------------------------------------------------------------------------
template<int AMODE, bool RELU>
__global__ __launch_bounds__(256) void gemm_kernel(
    const float* __restrict__ Afp, const float* __restrict__ Ebuf,
    const float* __restrict__ inA, const float* __restrict__ inV,
    const float* __restrict__ inL, const float* __restrict__ qmask,
    const float* __restrict__ spk_emb, const float* __restrict__ he_w,
    const ushort_t* __restrict__ WT, const float* __restrict__ bias,
    float* __restrict__ C0, float* __restrict__ C1, float* __restrict__ C2,
    int layer)
{
  const int tid = threadIdx.x;
  const int wave = tid>>6, lane = tid&63;
  const int row0 = blockIdx.x*32, col0 = blockIdx.y*128;

  const ushort_t* Wsel; float* Cout; const float* bsel;
  if (AMODE==2){
    int z = blockIdx.z;
    Wsel = WT + (size_t)(4 + z*4 + layer)*MATSZ;
    Cout = (z==0)? C0 : (z==1)? C1 : C2;
    bsel = (z==2)? bias + layer*512 : nullptr;
  } else { Wsel = WT; Cout = C0; bsel = bias; }

  __shared__ __align__(16) ushort_t As[32][72];
  __shared__ __align__(16) ushort_t Bs[128][72];

  // A staging: thread -> row ar (0..31), cols ac8..ac8+7 of the K-step
  const int ar = tid>>3, ac8 = (tid&7)*8;
  const int n = row0 + ar;
  const float* srcrow = nullptr; const float* spkrow = nullptr;
  const float* e1 = nullptr; const float* e2 = nullptr; float c1=0.f, c2=0.f;
  const float* grow = nullptr;
  if (AMODE==0){
    int d = n/162, rm = n-d*162, m = rm/54, i = rm-m*54, t = d*54+i;
    srcrow = ((m==0)? inL : (m==1)? inA : inV) + (size_t)t*512;
    if (m==0){
      float q0 = qmask[(i*16+d)*2];
      float q1 = qmask[(i*16+d)*2+1];
      spkrow = spk_emb + ((q1>q0) ? 512 : 0);
    }
  } else if (AMODE==1){
    int d = n/162, rm = n-d*162, m = rm/54, i = rm-m*54;
    int em = d*57+m, eu = d*57+3+i;
    float w1 = he_w[em], w2 = he_w[eu];
    float invdn = 1.0f/(w1+w2+1e-8f);
    c1 = w1*invdn; c2 = w2*invdn;
    e1 = Ebuf + (size_t)em*512;
    e2 = Ebuf + (size_t)eu*512;
  } else {
    grow = Afp + (size_t)n*512;
  }

  f32x4 acc00 = {0.f,0.f,0.f,0.f}, acc01 = {0.f,0.f,0.f,0.f};
  f32x4 acc10 = {0.f,0.f,0.f,0.f}, acc11 = {0.f,0.f,0.f,0.f};

  const int ml = lane&15, quad = lane>>4;
  const int wn = wave*32 + ml;

  for (int kk=0; kk<512; kk+=64){
    // ---- stage A (fp32 -> bf16) ----
    u16x8 av;
    if (AMODE==0){
      f32x4 xa = *(const f32x4*)(srcrow + kk + ac8);
      f32x4 xb = *(const f32x4*)(srcrow + kk + ac8 + 4);
      if (spkrow){
        f32x4 sa = *(const f32x4*)(spkrow + kk + ac8);
        f32x4 sb = *(const f32x4*)(spkrow + kk + ac8 + 4);
        #pragma unroll
        for (int j=0;j<4;j++){ xa[j]+=sa[j]; xb[j]+=sb[j]; }
      }
      #pragma unroll
      for (int j=0;j<4;j++){ av[j] = f2b(xa[j]); av[4+j] = f2b(xb[j]); }
    } else if (AMODE==1){
      f32x4 xa = *(const f32x4*)(e1 + kk + ac8);
      f32x4 xb = *(const f32x4*)(e1 + kk + ac8 + 4);
      f32x4 ya = *(const f32x4*)(e2 + kk + ac8);
      f32x4 yb = *(const f32x4*)(e2 + kk + ac8 + 4);
      #pragma unroll
      for (int j=0;j<4;j++){
        av[j]   = f2b(c1*xa[j] + c2*ya[j]);
        av[4+j] = f2b(c1*xb[j] + c2*yb[j]);
      }
    } else {
      f32x4 xa = *(const f32x4*)(grow + kk + ac8);
      f32x4 xb = *(const f32x4*)(grow + kk + ac8 + 4);
      #pragma unroll
      for (int j=0;j<4;j++){ av[j] = f2b(xa[j]); av[4+j] = f2b(xb[j]); }
    }
    *(u16x8*)&As[ar][ac8] = av;
    // ---- stage B (pre-transposed: WT[n][k], contiguous in k) ----
    #pragma unroll
    for (int rep=0; rep<4; rep++){
      int idx = rep*256 + tid;
      int bn = idx>>3, bk = (idx&7)*8;
      *(u16x8*)&Bs[bn][bk] = *(const u16x8*)(Wsel + (size_t)(col0+bn)*512 + kk + bk);
    }
    __syncthreads();
    #pragma unroll
    for (int kh=0; kh<2; kh++){
      s16x8 a0 = *(const s16x8*)&As[ml][kh*32 + quad*8];
      s16x8 a1 = *(const s16x8*)&As[16+ml][kh*32 + quad*8];
      s16x8 b0 = *(const s16x8*)&Bs[wn][kh*32 + quad*8];
      s16x8 b1 = *(const s16x8*)&Bs[wn+16][kh*32 + quad*8];
      acc00 = __builtin_amdgcn_mfma_f32_16x16x32_bf16(a0,b0,acc00,0,0,0);
      acc01 = __builtin_amdgcn_mfma_f32_16x16x32_bf16(a0,b1,acc01,0,0,0);
      acc10 = __builtin_amdgcn_mfma_f32_16x16x32_bf16(a1,b0,acc10,0,0,0);
      acc11 = __builtin_amdgcn_mfma_f32_16x16x32_bf16(a1,b1,acc11,0,0,0);
    }
    __syncthreads();
  }

  // epilogue: C/D layout col=lane&15, row=quad*4+reg
  int cA = col0 + wave*32 + ml;
  int cB = cA + 16;
  float bv0 = bsel ? bsel[cA] : 0.f;
  float bv1 = bsel ? bsel[cB] : 0.f;
  #pragma unroll
  for (int mi=0; mi<2; mi++){
    f32x4 aa = mi ? acc10 : acc00;
    f32x4 ab = mi ? acc11 : acc01;
    int rb = row0 + mi*16 + quad*4;
    #pragma unroll
    for (int r=0;r<4;r++){
      float v0 = aa[r]+bv0, v1 = ab[r]+bv1;
      if (RELU){ v0 = fmaxf(v0,0.f); v1 = fmaxf(v1,0.f); }
      Cout[(size_t)(rb+r)*512 + cA] = v0;
      Cout[(size_t)(rb+r)*512 + cB] = v1;
    }
  }
}

// ---------------------------------------------------------------------------
// Hyperedge aggregation: e[edge] = (sum_nnz w*x[node])/(sum w + eps) + attr
// grid 912 blocks, 256 threads (2 cols each)
// ---------------------------------------------------------------------------
__global__ __launch_bounds__(256) void edge_kernel(const float* __restrict__ X,
    const float* __restrict__ ew, const int* __restrict__ het,
    const float* __restrict__ at1, const float* __restrict__ at2,
    float* __restrict__ E)
{
  int e = blockIdx.x;
  int d = e/57, r = e - d*57;
  int col = threadIdx.x*2;
  float sx=0.f, sy=0.f, de=0.f;
  if (r < 3){  // modality hyperedge: 54 nodes, contiguous rows
    int nnz0 = d*324 + r*54;
    const float* row = X + ((size_t)(d*162 + r*54))*512 + col;
    for (int i=0;i<54;i++){
      float w = ew[nnz0+i];
      float2 x = *(const float2*)row;
      sx += w*x.x; sy += w*x.y; de += w;
      row += 512;
    }
  } else {     // utterance hyperedge: (l,a,v) of utterance i
    int i = r-3;
    int nnz0 = d*324 + 162 + i*3;
    #pragma unroll
    for (int m=0;m<3;m++){
      float w = ew[nnz0+m];
      const float* row = X + ((size_t)(d*162 + m*54 + i))*512 + col;
      float2 x = *(const float2*)row;
      sx += w*x.x; sy += w*x.y; de += w;
    }
  }
  float invde = 1.0f/(de + 1e-8f);
  const float* at = het[e] ? at1 : at2;  // attr1*tfl + attr2*(1-tfl)
  float2 o;
  o.x = sx*invde + at[col];
  o.y = sy*invde + at[col+1];
  *(float2*)(E + (size_t)e*512 + col) = o;
}

// ---------------------------------------------------------------------------
// RGCN group sums: per (dialogue,modality) group, per speaker: sum h0, h1.
// S layout [48][4][512]: 0=S0 spk0, 1=S0 spk1, 2=S1 spk0, 3=S1 spk1
// grid (48,2), block 256 (1 col each)
// ---------------------------------------------------------------------------
__global__ __launch_bounds__(256) void skernel(const float* __restrict__ H0,
    const float* __restrict__ H1, const float* __restrict__ qmask,
    float* __restrict__ S)
{
  int g = blockIdx.x;
  int d = g/3, m = g - d*3;
  int col = blockIdx.y*256 + threadIdx.x;
  float s00=0.f, s01=0.f, s10=0.f, s11=0.f;
  size_t base = ((size_t)(d*162 + m*54))*512 + col;
  for (int i=0;i<54;i++){
    float q0 = qmask[(i*16+d)*2];
    float q1 = qmask[(i*16+d)*2+1];
    float h0 = H0[base + (size_t)i*512];
    float h1 = H1[base + (size_t)i*512];
    if (q1>q0){ s01 += h0; s11 += h1; } else { s00 += h0; s10 += h1; }
  }
  float* Sg = S + (size_t)g*2048;
  Sg[col] = s00; Sg[512+col] = s01; Sg[1024+col] = s10; Sg[1536+col] = s11;
}

// ---------------------------------------------------------------------------
// RGCN combine: f = relu((S1[sp]+S0[1-sp]-h1)/53 + hs); g += f
// LAST: also write d_out = out_hg + g (fp32) and accumulate sum(f^2)
// grid 2592 blocks, 256 threads (2 cols each)
// ---------------------------------------------------------------------------
template<bool LAST>
__global__ __launch_bounds__(256) void fkernel(
    const float* __restrict__ Gin, const float* __restrict__ H1,
    const float* __restrict__ HS, const float* __restrict__ S,
    const float* __restrict__ qmask, float* __restrict__ Gout,
    const float* __restrict__ OUThg, float* __restrict__ dout,
    float* __restrict__ acc)
{
  int n = blockIdx.x, tid = threadIdx.x;
  int d = n/162, rm = n - d*162, m = rm/54, i = rm - m*54;
  int g = d*3 + m;
  float q0 = qmask[(i*16+d)*2];
  float q1 = qmask[(i*16+d)*2+1];
  int sp = (q1>q0) ? 1 : 0;
  const float* Sg = S + (size_t)g*2048;
  int col = tid*2;
  size_t off = (size_t)n*512 + col;
  float2 h1 = *(const float2*)(H1+off);
  float2 hs = *(const float2*)(HS+off);
  float2 gi = *(const float2*)(Gin+off);
  const float inv = 1.0f/(53.0f + 1e-8f);
  float s1a = Sg[(size_t)(2+sp)*512+col], s1b = Sg[(size_t)(2+sp)*512+col+1];
  float s0a = Sg[(size_t)(1-sp)*512+col], s0b = Sg[(size_t)(1-sp)*512+col+1];
  float fx = fmaxf((s1a + s0a - h1.x)*inv + hs.x, 0.0f);
  float fy = fmaxf((s1b + s0b - h1.y)*inv + hs.y, 0.0f);
  float2 gn; gn.x = gi.x+fx; gn.y = gi.y+fy;
  *(float2*)(Gout+off) = gn;
  if (LAST){
    float2 oh = *(const float2*)(OUThg+off);
    float2 o2; o2.x = oh.x+gn.x; o2.y = oh.y+gn.y;
    *(float2*)(dout+off) = o2;
    __shared__ float red[256];
    red[tid] = fx*fx + fy*fy;
    __syncthreads();
    #pragma unroll
    for (int s2=128; s2>0; s2>>=1){
      if (tid<s2) red[tid]+=red[tid+s2];
      __syncthreads();
    }
    if (tid==0) atomicAdd(acc, red[0]);
  }
}

__global__ void scalar_kernel(const float* __restrict__ acc, float* __restrict__ dout){
  if (threadIdx.x==0) dout[(size_t)NNODE*512] = acc[0] * (1.0f/1327104.0f);
}

// ---------------------------------------------------------------------------
extern "C" void kernel_launch(void* const* d_in, const int* in_sizes, int n_in,
                              void* d_out, int out_size, void* d_ws, size_t ws_size,
                              hipStream_t stream)
{
  const float* A_in   = (const float*)d_in[0];
  const float* V_in   = (const float*)d_in[1];
  const float* L_in   = (const float*)d_in[2];
  const float* qmask  = (const float*)d_in[3];
  const float* spk    = (const float*)d_in[4];
  const float* fc1_W  = (const float*)d_in[5];
  const float* fc1_b  = (const float*)d_in[6];
  const float* he_w   = (const float*)d_in[7];
  const float* ew_w   = (const float*)d_in[8];
  const float* attr1  = (const float*)d_in[9];
  const float* attr2  = (const float*)d_in[10];
  const float* hc_W   = (const float*)d_in[11];
  const float* hc_b   = (const float*)d_in[12];
  const float* m3_W0  = (const float*)d_in[13];
  const float* m3_W1  = (const float*)d_in[14];
  const float* m3_Ws  = (const float*)d_in[15];
  const float* m3_b   = (const float*)d_in[16];
  const int*   het    = (const int*)d_in[18];
  float* dout = (float*)d_out;

  // workspace layout (all 16B-aligned; total ~40 MB)
  char* ws = (char*)d_ws;
  ushort_t* WT = (ushort_t*)ws;                     // 16 * 512*512 bf16 = 8 MB
  float* X1  = (float*)(ws + (size_t)16*MATSZ*2);
  float* OUT = X1  + (size_t)NNODE*512;
  float* H1  = OUT + (size_t)NNODE*512;
  float* HS  = H1  + (size_t)NNODE*512;
  float* G   = HS  + (size_t)NNODE*512;
  float* H0  = G   + (size_t)NNODE*512;             // union: EB / H0
  float* EB  = H0;
  float* S   = H0  + (size_t)NNODE*512;
  float* acc = S   + 48*4*512;

  transpose_weights<<<dim3(8,8,16),256,0,stream>>>(fc1_W, hc_W, m3_W0, m3_W1, m3_Ws, WT, acc);

  // x1 = feats @ fc1_W + b
  gemm_kernel<0,false><<<dim3(81,4,1),256,0,stream>>>(
      nullptr, nullptr, A_in, V_in, L_in, qmask, spk, nullptr,
      WT, fc1_b, X1, nullptr, nullptr, 0);

  // hypergraph conv x3
  const float* src = X1;
  for (int ll=0; ll<3; ll++){
    edge_kernel<<<NEDGE,256,0,stream>>>(src, ew_w, het, attr1, attr2, EB);
    gemm_kernel<1,true><<<dim3(81,4,1),256,0,stream>>>(
        nullptr, EB, nullptr, nullptr, nullptr, nullptr, nullptr, he_w,
        WT + (size_t)(1+ll)*MATSZ, hc_b + (size_t)ll*512, OUT, nullptr, nullptr, 0);
    src = OUT;
  }

  // RGCN denoise x4
  for (int kk=0; kk<4; kk++){
    const float* gin = (kk==0) ? X1 : G;
    gemm_kernel<2,false><<<dim3(81,4,3),256,0,stream>>>(
        gin, nullptr, nullptr, nullptr, nullptr, nullptr, nullptr, nullptr,
        WT, m3_b, H0, H1, HS, kk);
    skernel<<<dim3(48,2),256,0,stream>>>(H0, H1, qmask, S);
    if (kk<3)
      fkernel<false><<<NNODE,256,0,stream>>>(gin, H1, HS, S, qmask, G,
                                             nullptr, nullptr, nullptr);
    else
      fkernel<true><<<NNODE,256,0,stream>>>(gin, H1, HS, S, qmask, G,
                                            OUT, dout, acc);
  }

  scalar_kernel<<<1,64,0,stream>>>(acc, dout);
  (void)in_sizes; (void)n_in; (void)out_size; (void)ws_size;
}

// Round 3
// 314.037 us; speedup vs baseline: 1.0383x; 1.0383x over previous
//
#include <hip/hip_runtime.h>

typedef unsigned short ushort_t;
typedef __attribute__((ext_vector_type(4))) float f32x4;
typedef __attribute__((ext_vector_type(8))) short s16x8;
typedef __attribute__((ext_vector_type(8))) unsigned short u16x8;

#define NB 16         // dialogues
#define NL 54         // utterances per dialogue
#define NT (NB*NL)    // 864
#define NNODE (3*NT)  // 2592
#define NEDGE 912     // hyperedges = 16*(54+3)
#define MATSZ (512*512)

__device__ __forceinline__ ushort_t f2b(float f){
  union {unsigned int i; float f;} x; x.f = f;
  unsigned int r = (x.i + 0x7fffu + ((x.i>>16)&1u))>>16;
  return (ushort_t)r;
}

__device__ __forceinline__ void async_copy16(const ushort_t* g, ushort_t* l){
  __builtin_amdgcn_global_load_lds((const __attribute__((address_space(1))) void*)g,
                                   (__attribute__((address_space(3))) void*)l, 16, 0, 0);
}

// ---------------------------------------------------------------------------
// Kernel 0: transpose+convert 16 fp32 weights [K,N] -> bf16 WT[w][n][k];
// zero acc + counter.  grid (8,8,16), block 256
// ---------------------------------------------------------------------------
__global__ __launch_bounds__(256) void transpose_weights(
    const float* __restrict__ fc1, const float* __restrict__ hc,
    const float* __restrict__ m0, const float* __restrict__ m1,
    const float* __restrict__ ms, ushort_t* __restrict__ WT,
    float* __restrict__ acc, unsigned int* __restrict__ counter)
{
  if (blockIdx.x==0 && blockIdx.y==0 && blockIdx.z==0 && threadIdx.x==0){
    *acc = 0.0f; *counter = 0u;
  }
  int w = blockIdx.z;
  const float* src = (w==0) ? fc1
                   : (w<4)  ? hc + (size_t)(w-1)*MATSZ
                   : (w<8)  ? m0 + (size_t)(w-4)*MATSZ
                   : (w<12) ? m1 + (size_t)(w-8)*MATSZ
                            : ms + (size_t)(w-12)*MATSZ;
  ushort_t* dst = WT + (size_t)w*MATSZ;
  __shared__ float tile[64][65];
  int r0 = blockIdx.x*64, c0 = blockIdx.y*64;
  #pragma unroll
  for (int j=0;j<16;j++){
    int idx = j*256 + threadIdx.x;
    int r = idx>>6, c = idx&63;
    tile[r][c] = src[(size_t)(r0+r)*512 + c0 + c];
  }
  __syncthreads();
  #pragma unroll
  for (int j=0;j<16;j++){
    int idx = j*256 + threadIdx.x;
    int r = idx>>6, c = idx&63;
    dst[(size_t)(c0+r)*512 + r0 + c] = f2b(tile[c][r]);
  }
}

// ---------------------------------------------------------------------------
// GEMM, tile 64x128, 4 waves (2x2), per-wave 32x64 = 2m x 4n frags.
// B staged via global_load_lds (16B) into XOR-swizzled unpadded LDS.
// AMODE 0: A = feats (a/v/l + spk_emb via qmask argmax), W=fc1
// AMODE 1: A = 2-incidence hyperedge combine from Ebuf, W passed in
// AMODE 2 (RGCN layer): z=0 -> H1=gin@W1, z=1 -> HS=gin@Wself+b,
//          z=2 (blocks x<4) -> Sp[96x1024] = Gsum@[W0|W1]
// ---------------------------------------------------------------------------
template<int AMODE, bool RELU>
__global__ __launch_bounds__(256) void gemm_kernel(
    const float* __restrict__ Afp, const float* __restrict__ Ebuf,
    const float* __restrict__ inA, const float* __restrict__ inV,
    const float* __restrict__ inL, const float* __restrict__ qmask,
    const float* __restrict__ spk_emb, const float* __restrict__ he_w,
    const ushort_t* __restrict__ WT, const float* __restrict__ bias,
    float* __restrict__ C0, float* __restrict__ C1, float* __restrict__ C2,
    int layer)
{
  const int tid = threadIdx.x;
  const int wave = tid>>6, lane = tid&63;
  const int ml = lane&15, quad = lane>>4;
  const int wr = wave>>1, wc = wave&1;
  int row0 = blockIdx.x*64, col0 = blockIdx.y*128;
  int M = NNODE, cst = 512, cbase = 0;
  const ushort_t* Wsel = WT; float* Cout = C0; const float* bsel = bias;
  const float* Asrc = Afp;
  if (AMODE==2){
    int z = blockIdx.z;
    if (z==0){ Wsel = WT + (size_t)(8+layer)*MATSZ; Cout = C0; bsel = nullptr; }
    else if (z==1){ Wsel = WT + (size_t)(12+layer)*MATSZ; Cout = C1; bsel = bias + layer*512; }
    else {
      if (blockIdx.x >= 4) return;
      int colh = blockIdx.x & 1;
      row0 = (blockIdx.x>>1)*64;
      Wsel = WT + (size_t)(4 + colh*4 + layer)*MATSZ;
      Cout = C2; bsel = nullptr; M = 96; cst = 1024; cbase = colh*512;
      Asrc = Ebuf;   // Gsum passed in the Ebuf slot
    }
  }

  __shared__ __align__(16) ushort_t As[64][80];
  __shared__ __align__(16) ushort_t Bs[128*64];

  // ---- per-thread A staging metadata: rows n0 = row0+ar, n1 = n0+32 ----
  const int ar = tid>>3, ac8 = (tid&7)*8;
  const float *sr0=nullptr,*sr1=nullptr,*sp0=nullptr,*sp1=nullptr;
  const float *e10=nullptr,*e20=nullptr,*e11=nullptr,*e21=nullptr;
  float c10=0.f,c20=0.f,c11=0.f,c21=0.f;
  const float *g0=nullptr,*g1=nullptr;
  {
    int n0 = row0+ar;     if (n0 > M-1) n0 = M-1;
    int n1 = row0+ar+32;  if (n1 > M-1) n1 = M-1;
    if (AMODE==0){
      int d=n0/162, rm=n0-d*162, m=rm/54, i=rm-m*54, t=d*54+i;
      sr0 = ((m==0)? inL : (m==1)? inA : inV) + (size_t)t*512;
      if (m==0) sp0 = spk_emb + ((qmask[(i*16+d)*2+1]>qmask[(i*16+d)*2])?512:0);
      d=n1/162; rm=n1-d*162; m=rm/54; i=rm-m*54; t=d*54+i;
      sr1 = ((m==0)? inL : (m==1)? inA : inV) + (size_t)t*512;
      if (m==0) sp1 = spk_emb + ((qmask[(i*16+d)*2+1]>qmask[(i*16+d)*2])?512:0);
    } else if (AMODE==1){
      int d=n0/162, rm=n0-d*162, m=rm/54, i=rm-m*54;
      int em=d*57+m, eu=d*57+3+i;
      float w1=he_w[em], w2=he_w[eu], inv=1.0f/(w1+w2+1e-8f);
      c10=w1*inv; c20=w2*inv; e10=Ebuf+(size_t)em*512; e20=Ebuf+(size_t)eu*512;
      d=n1/162; rm=n1-d*162; m=rm/54; i=rm-m*54;
      em=d*57+m; eu=d*57+3+i;
      w1=he_w[em]; w2=he_w[eu]; inv=1.0f/(w1+w2+1e-8f);
      c11=w1*inv; c21=w2*inv; e11=Ebuf+(size_t)em*512; e21=Ebuf+(size_t)eu*512;
    } else {
      g0 = Asrc + (size_t)n0*512;
      g1 = Asrc + (size_t)n1*512;
    }
  }

  f32x4 acc[2][4];
  #pragma unroll
  for (int mi=0;mi<2;mi++)
    #pragma unroll
    for (int j=0;j<4;j++) acc[mi][j] = (f32x4){0.f,0.f,0.f,0.f};

  const int lr = lane>>3;       // 0..7 (row-in-group for B DMA)
  const int lchunk = lane&7;    // 0..7
  const int bswz = (lchunk ^ lr)*8;

  for (int kk=0; kk<512; kk+=64){
    // ---- stage A rows (fp32 -> bf16) ----
    u16x8 av0, av1;
    if (AMODE==0){
      f32x4 xa=*(const f32x4*)(sr0+kk+ac8), xb=*(const f32x4*)(sr0+kk+ac8+4);
      if (sp0){
        f32x4 sa=*(const f32x4*)(sp0+kk+ac8), sb=*(const f32x4*)(sp0+kk+ac8+4);
        #pragma unroll
        for(int j=0;j<4;j++){ xa[j]+=sa[j]; xb[j]+=sb[j]; }
      }
      #pragma unroll
      for(int j=0;j<4;j++){ av0[j]=f2b(xa[j]); av0[4+j]=f2b(xb[j]); }
      xa=*(const f32x4*)(sr1+kk+ac8); xb=*(const f32x4*)(sr1+kk+ac8+4);
      if (sp1){
        f32x4 sa=*(const f32x4*)(sp1+kk+ac8), sb=*(const f32x4*)(sp1+kk+ac8+4);
        #pragma unroll
        for(int j=0;j<4;j++){ xa[j]+=sa[j]; xb[j]+=sb[j]; }
      }
      #pragma unroll
      for(int j=0;j<4;j++){ av1[j]=f2b(xa[j]); av1[4+j]=f2b(xb[j]); }
    } else if (AMODE==1){
      f32x4 xa=*(const f32x4*)(e10+kk+ac8), xb=*(const f32x4*)(e10+kk+ac8+4);
      f32x4 ya=*(const f32x4*)(e20+kk+ac8), yb=*(const f32x4*)(e20+kk+ac8+4);
      #pragma unroll
      for(int j=0;j<4;j++){ av0[j]=f2b(c10*xa[j]+c20*ya[j]); av0[4+j]=f2b(c10*xb[j]+c20*yb[j]); }
      xa=*(const f32x4*)(e11+kk+ac8); xb=*(const f32x4*)(e11+kk+ac8+4);
      ya=*(const f32x4*)(e21+kk+ac8); yb=*(const f32x4*)(e21+kk+ac8+4);
      #pragma unroll
      for(int j=0;j<4;j++){ av1[j]=f2b(c11*xa[j]+c21*ya[j]); av1[4+j]=f2b(c11*xb[j]+c21*yb[j]); }
    } else {
      f32x4 xa=*(const f32x4*)(g0+kk+ac8), xb=*(const f32x4*)(g0+kk+ac8+4);
      #pragma unroll
      for(int j=0;j<4;j++){ av0[j]=f2b(xa[j]); av0[4+j]=f2b(xb[j]); }
      xa=*(const f32x4*)(g1+kk+ac8); xb=*(const f32x4*)(g1+kk+ac8+4);
      #pragma unroll
      for(int j=0;j<4;j++){ av1[j]=f2b(xa[j]); av1[4+j]=f2b(xb[j]); }
    }
    *(u16x8*)&As[ar][ac8]    = av0;
    *(u16x8*)&As[ar+32][ac8] = av1;

    // ---- stage B via async DMA: wave covers rows [wave*32, wave*32+32) ----
    #pragma unroll
    for (int rep=0; rep<4; rep++){
      int bn0 = wave*32 + rep*8;
      const ushort_t* src = Wsel + (size_t)(col0 + bn0 + lr)*512 + kk + bswz;
      async_copy16(src, &Bs[bn0*64]);
    }
    __syncthreads();

    #pragma unroll
    for (int kh=0; kh<2; kh++){
      s16x8 a0 = *(const s16x8*)&As[wr*32 + ml][kh*32 + quad*8];
      s16x8 a1 = *(const s16x8*)&As[wr*32 + 16 + ml][kh*32 + quad*8];
      s16x8 b[4];
      #pragma unroll
      for (int j=0;j<4;j++){
        int bn = wc*64 + j*16 + ml;
        b[j] = *(const s16x8*)&Bs[bn*64 + (((kh*4+quad) ^ (bn&7))<<3)];
      }
      #pragma unroll
      for (int j=0;j<4;j++){
        acc[0][j] = __builtin_amdgcn_mfma_f32_16x16x32_bf16(a0,b[j],acc[0][j],0,0,0);
        acc[1][j] = __builtin_amdgcn_mfma_f32_16x16x32_bf16(a1,b[j],acc[1][j],0,0,0);
      }
    }
    __syncthreads();
  }

  // ---- epilogue (C/D: col=lane&15, row=quad*4+reg) ----
  #pragma unroll
  for (int j=0;j<4;j++){
    int wcol = col0 + wc*64 + j*16 + ml;
    float bv = bsel ? bsel[wcol] : 0.f;
    int c = cbase + wcol;
    #pragma unroll
    for (int mi=0;mi<2;mi++){
      int rb = row0 + wr*32 + mi*16 + quad*4;
      f32x4 a = acc[mi][j];
      #pragma unroll
      for (int r=0;r<4;r++){
        int rr = rb + r;
        if (rr < M){
          float v = a[r] + bv;
          if (RELU) v = fmaxf(v, 0.f);
          Cout[(size_t)rr*cst + c] = v;
        }
      }
    }
  }
}

// ---------------------------------------------------------------------------
// Hyperedge aggregation: e[edge] = (sum w*x)/(sum w + eps) + attr
// grid 912 blocks, 256 threads (2 cols each)
// ---------------------------------------------------------------------------
__global__ __launch_bounds__(256) void edge_kernel(const float* __restrict__ X,
    const float* __restrict__ ew, const int* __restrict__ het,
    const float* __restrict__ at1, const float* __restrict__ at2,
    float* __restrict__ E)
{
  int e = blockIdx.x;
  int d = e/57, r = e - d*57;
  int col = threadIdx.x*2;
  float sx=0.f, sy=0.f, de=0.f;
  if (r < 3){
    int nnz0 = d*324 + r*54;
    const float* row = X + ((size_t)(d*162 + r*54))*512 + col;
    for (int i=0;i<54;i++){
      float w = ew[nnz0+i];
      float2 x = *(const float2*)row;
      sx += w*x.x; sy += w*x.y; de += w;
      row += 512;
    }
  } else {
    int i = r-3;
    int nnz0 = d*324 + 162 + i*3;
    #pragma unroll
    for (int m=0;m<3;m++){
      float w = ew[nnz0+m];
      const float* row = X + ((size_t)(d*162 + m*54 + i))*512 + col;
      float2 x = *(const float2*)row;
      sx += w*x.x; sy += w*x.y; de += w;
    }
  }
  float invde = 1.0f/(de + 1e-8f);
  const float* at = het[e] ? at1 : at2;
  float2 o;
  o.x = sx*invde + at[col];
  o.y = sy*invde + at[col+1];
  *(float2*)(E + (size_t)e*512 + col) = o;
}

// ---------------------------------------------------------------------------
// Gsum of X1 (first RGCN layer input): per (group, speaker) column sums.
// grid (48,2), 256 threads (1 col each)
// ---------------------------------------------------------------------------
__global__ __launch_bounds__(256) void gsum_kernel(const float* __restrict__ X,
    const float* __restrict__ qmask, float* __restrict__ Gsum)
{
  int g = blockIdx.x, d = g/3;
  int col = blockIdx.y*256 + threadIdx.x;
  __shared__ unsigned char spks[54];
  if (threadIdx.x < 54){
    int i = threadIdx.x;
    spks[i] = qmask[(i*16+d)*2+1] > qmask[(i*16+d)*2];
  }
  __syncthreads();
  size_t base = (size_t)g*54*512 + col;
  float s0=0.f, s1=0.f;
  for (int i=0;i<54;i++){
    float x = X[base + (size_t)i*512];
    if (spks[i]) s1 += x; else s0 += x;
  }
  Gsum[(size_t)(g*2)*512 + col]   = s0;
  Gsum[(size_t)(g*2+1)*512 + col] = s1;
}

// ---------------------------------------------------------------------------
// Fused RGCN combine: f = relu((S1[sp]-h1+S0[1-sp])/53 + hs); g += f.
// Emits Gsum of new g for next layer. LAST: writes dout, accumulates
// sum(f^2), last block finalizes the denoise scalar.
// grid (48,2), 256 threads (1 col each)
// ---------------------------------------------------------------------------
template<bool LAST>
__global__ __launch_bounds__(256) void sf_kernel(
    const float* __restrict__ Gin, const float* __restrict__ H1,
    const float* __restrict__ HS, const float* __restrict__ Sp,
    const float* __restrict__ qmask, float* __restrict__ Gout,
    float* __restrict__ Gsum, const float* __restrict__ OUThg,
    float* __restrict__ dout, float* __restrict__ acc,
    unsigned int* __restrict__ counter)
{
  int g = blockIdx.x, d = g/3;
  int col = blockIdx.y*256 + threadIdx.x;
  __shared__ unsigned char spks[54];
  if (threadIdx.x < 54){
    int i = threadIdx.x;
    spks[i] = qmask[(i*16+d)*2+1] > qmask[(i*16+d)*2];
  }
  __syncthreads();
  // Sp rows: g*2+spk, cols 0..511 = Gsum@W0 (S0), 512..1023 = Gsum@W1 (S1)
  const float* r0 = Sp + (size_t)(g*2)*1024;
  const float* r1 = Sp + (size_t)(g*2+1)*1024;
  float S1_0 = r0[512+col];  // S1 when sp=0
  float S1_1 = r1[512+col];  // S1 when sp=1
  float S0_0 = r1[col];      // S0[1-sp] when sp=0
  float S0_1 = r0[col];      // S0[1-sp] when sp=1
  const float inv = 1.0f/(53.0f + 1e-8f);
  size_t base = (size_t)g*54*512 + col;
  float gs0=0.f, gs1=0.f, sumsq=0.f;
  for (int i=0;i<54;i++){
    size_t off = base + (size_t)i*512;
    int sp = spks[i];
    float S1 = sp ? S1_1 : S1_0;
    float S0 = sp ? S0_1 : S0_0;
    float h1 = H1[off], hs = HS[off], gi = Gin[off];
    float f = fmaxf((S1 - h1 + S0)*inv + hs, 0.f);
    float gn = gi + f;
    Gout[off] = gn;
    if (sp) gs1 += gn; else gs0 += gn;
    if (LAST){
      sumsq += f*f;
      dout[off] = OUThg[off] + gn;
    }
  }
  Gsum[(size_t)(g*2)*512 + col]   = gs0;
  Gsum[(size_t)(g*2+1)*512 + col] = gs1;
  if (LAST){
    __shared__ float red[256];
    red[threadIdx.x] = sumsq;
    __syncthreads();
    #pragma unroll
    for (int s=128; s>0; s>>=1){
      if (threadIdx.x < s) red[threadIdx.x] += red[threadIdx.x+s];
      __syncthreads();
    }
    if (threadIdx.x == 0){
      atomicAdd(acc, red[0]);
      __threadfence();
      unsigned int old = atomicAdd(counter, 1u);
      if (old == 95u){
        float tot = atomicAdd(acc, 0.0f);   // atomic read (returns current)
        dout[(size_t)NNODE*512] = tot * (1.0f/1327104.0f);
      }
    }
  }
}

// ---------------------------------------------------------------------------
extern "C" void kernel_launch(void* const* d_in, const int* in_sizes, int n_in,
                              void* d_out, int out_size, void* d_ws, size_t ws_size,
                              hipStream_t stream)
{
  const float* A_in   = (const float*)d_in[0];
  const float* V_in   = (const float*)d_in[1];
  const float* L_in   = (const float*)d_in[2];
  const float* qmask  = (const float*)d_in[3];
  const float* spk    = (const float*)d_in[4];
  const float* fc1_W  = (const float*)d_in[5];
  const float* fc1_b  = (const float*)d_in[6];
  const float* he_w   = (const float*)d_in[7];
  const float* ew_w   = (const float*)d_in[8];
  const float* attr1  = (const float*)d_in[9];
  const float* attr2  = (const float*)d_in[10];
  const float* hc_W   = (const float*)d_in[11];
  const float* hc_b   = (const float*)d_in[12];
  const float* m3_W0  = (const float*)d_in[13];
  const float* m3_W1  = (const float*)d_in[14];
  const float* m3_Ws  = (const float*)d_in[15];
  const float* m3_b   = (const float*)d_in[16];
  const int*   het    = (const int*)d_in[18];
  float* dout = (float*)d_out;

  // workspace layout
  char* ws = (char*)d_ws;
  ushort_t* WT = (ushort_t*)ws;                       // 16 * 256K bf16 = 8 MB
  float* X1   = (float*)(ws + (size_t)16*MATSZ*2);
  float* OUT  = X1  + (size_t)NNODE*512;
  float* H1   = OUT + (size_t)NNODE*512;
  float* HS   = H1  + (size_t)NNODE*512;
  float* G    = HS  + (size_t)NNODE*512;
  float* EB   = G   + (size_t)NNODE*512;              // NEDGE*512
  float* Gsum = EB  + (size_t)NEDGE*512;              // 96*512
  float* Sp   = Gsum + 96*512;                        // 96*1024
  float* acc  = Sp  + 96*1024;
  unsigned int* counter = (unsigned int*)(acc + 1);

  transpose_weights<<<dim3(8,8,16),256,0,stream>>>(fc1_W, hc_W, m3_W0, m3_W1,
                                                   m3_Ws, WT, acc, counter);

  // x1 = feats @ fc1_W + b
  gemm_kernel<0,false><<<dim3(41,4,1),256,0,stream>>>(
      nullptr, nullptr, A_in, V_in, L_in, qmask, spk, nullptr,
      WT, fc1_b, X1, nullptr, nullptr, 0);

  gsum_kernel<<<dim3(48,2),256,0,stream>>>(X1, qmask, Gsum);

  // hypergraph conv x3
  const float* src = X1;
  for (int ll=0; ll<3; ll++){
    edge_kernel<<<NEDGE,256,0,stream>>>(src, ew_w, het, attr1, attr2, EB);
    gemm_kernel<1,true><<<dim3(41,4,1),256,0,stream>>>(
        nullptr, EB, nullptr, nullptr, nullptr, nullptr, nullptr, he_w,
        WT + (size_t)(1+ll)*MATSZ, hc_b + (size_t)ll*512, OUT, nullptr, nullptr, 0);
    src = OUT;
  }

  // RGCN denoise x4
  for (int kk=0; kk<4; kk++){
    const float* gin = (kk==0) ? X1 : G;
    gemm_kernel<2,false><<<dim3(41,4,3),256,0,stream>>>(
        gin, Gsum, nullptr, nullptr, nullptr, nullptr, nullptr, nullptr,
        WT, m3_b, H1, HS, Sp, kk);
    if (kk<3)
      sf_kernel<false><<<dim3(48,2),256,0,stream>>>(
          gin, H1, HS, Sp, qmask, G, Gsum, nullptr, nullptr, acc, counter);
    else
      sf_kernel<true><<<dim3(48,2),256,0,stream>>>(
          gin, H1, HS, Sp, qmask, G, Gsum, OUT, dout, acc, counter);
  }

  (void)in_sizes; (void)n_in; (void)out_size; (void)ws_size;
}